// Round 2
// baseline (41.462 us; speedup 1.0000x reference)
//
#include <hip/hip_runtime.h>
#include <math.h>

#define NB 4
#define CC 128
#define HW 784        // 28*28
#define KK 64
#define DD 512
#define TD 8          // d-rows per block

// Kernel 1: per-pixel inverse L2 norm over channels.
__global__ __launch_bounds__(256) void rinv_kernel(const float* __restrict__ x,
                                                   float* __restrict__ rinv) {
    int idx = blockIdx.x * 256 + threadIdx.x;   // 0 .. NB*HW-1
    if (idx >= NB * HW) return;
    int n = idx / HW;
    int p = idx - n * HW;
    const float* xp = x + (size_t)n * CC * HW + p;
    float s = 0.f;
    #pragma unroll
    for (int c = 0; c < CC; ++c) {
        float v = xp[(size_t)c * HW];           // coalesced across threads (consecutive p)
        s = fmaf(v, v, s);
    }
    rinv[idx] = 1.0f / fmaxf(sqrtf(s), 1e-12f);
}

// Kernel 2: fused (1x1 conv GEMM + normalize-scale + bias) -> per-row softmax
// weighted mean over P -> broadcast over k.
// Block = 256 threads, owns (n, 8 consecutive d rows). Grid = 4 * 64 = 256.
__global__ __launch_bounds__(256) void feat_softmax_kernel(
    const float* __restrict__ x, const float* __restrict__ w,
    const float* __restrict__ b, const float* __restrict__ rinv,
    float* __restrict__ out)
{
    __shared__ float w_s[TD][CC];        // 4 KB
    __shared__ float feat_s[TD][HW];     // 25 KB

    const int tid = threadIdx.x;
    const int n  = blockIdx.x >> 6;      // 64 d-groups per n
    const int d0 = (blockIdx.x & 63) * TD;

    // stage the 8x128 weight tile (contiguous 1024 floats)
    {
        const float* wsrc = w + (size_t)d0 * CC;
        for (int i = tid; i < TD * CC; i += 256) ((float*)w_s)[i] = wsrc[i];
    }
    __syncthreads();

    const float* xb = x + (size_t)n * CC * HW;
    float acc[TD][4];
    #pragma unroll
    for (int j = 0; j < TD; ++j)
        #pragma unroll
        for (int i = 0; i < 4; ++i) acc[j][i] = 0.f;

    // GEMM main loop: thread owns pixels {tid, tid+256, tid+512, tid+768?}
    for (int c = 0; c < CC; ++c) {
        const float* xc = xb + (size_t)c * HW;
        float xv0 = xc[tid];
        float xv1 = xc[tid + 256];
        float xv2 = xc[tid + 512];
        float xv3 = (tid < HW - 768) ? xc[tid + 768] : 0.f;
        #pragma unroll
        for (int j = 0; j < TD; ++j) {
            float wv = w_s[j][c];        // same addr for all lanes -> LDS broadcast
            acc[j][0] = fmaf(wv, xv0, acc[j][0]);
            acc[j][1] = fmaf(wv, xv1, acc[j][1]);
            acc[j][2] = fmaf(wv, xv2, acc[j][2]);
            acc[j][3] = fmaf(wv, xv3, acc[j][3]);
        }
    }

    // feat = rinv * dot + bias, staged to LDS
    const float* rv = rinv + n * HW;
    float r0 = rv[tid];
    float r1 = rv[tid + 256];
    float r2 = rv[tid + 512];
    float r3 = (tid < HW - 768) ? rv[tid + 768] : 0.f;
    #pragma unroll
    for (int j = 0; j < TD; ++j) {
        float bj = b[d0 + j];
        feat_s[j][tid]       = fmaf(acc[j][0], r0, bj);
        feat_s[j][tid + 256] = fmaf(acc[j][1], r1, bj);
        feat_s[j][tid + 512] = fmaf(acc[j][2], r2, bj);
        if (tid < HW - 768) feat_s[j][tid + 768] = fmaf(acc[j][3], r3, bj);
    }
    __syncthreads();

    // Per-row softmax-weighted mean over P=784; each wave handles 2 rows.
    const int lane = tid & 63;
    const int wave = tid >> 6;
    #pragma unroll
    for (int jj = 0; jj < TD / 4; ++jj) {
        const int j = wave * (TD / 4) + jj;
        float m = -INFINITY;
        for (int p = lane; p < HW; p += 64) m = fmaxf(m, feat_s[j][p]);
        #pragma unroll
        for (int off = 32; off; off >>= 1) m = fmaxf(m, __shfl_xor(m, off, 64));
        float s = 0.f, ws = 0.f;
        for (int p = lane; p < HW; p += 64) {
            float f = feat_s[j][p];
            float e = __expf(f - m);
            s += e;
            ws = fmaf(e, f, ws);
        }
        #pragma unroll
        for (int off = 32; off; off >>= 1) {
            s  += __shfl_xor(s, off, 64);
            ws += __shfl_xor(ws, off, 64);
        }
        float g = ws / s;
        // vlad[n,k,d] = g for all k: lane writes k = lane
        out[(size_t)n * KK * DD + (size_t)lane * DD + (d0 + j)] = g;
    }
}

extern "C" void kernel_launch(void* const* d_in, const int* in_sizes, int n_in,
                              void* d_out, int out_size, void* d_ws, size_t ws_size,
                              hipStream_t stream) {
    const float* x = (const float*)d_in[0];   // (4,128,28,28)
    const float* w = (const float*)d_in[1];   // (512,128)
    const float* b = (const float*)d_in[2];   // (512,)
    // d_in[3] = centroids (64,512): provably unused — softmax over the spatial
    // axis is invariant to the per-(k,d) constant shift, so vlad[n,k,d] is
    // identical for all k.
    float* rinv = (float*)d_ws;               // NB*HW floats = 12.5 KB
    float* out  = (float*)d_out;              // (4,64,512) fp32

    rinv_kernel<<<(NB * HW + 255) / 256, 256, 0, stream>>>(x, rinv);
    feat_softmax_kernel<<<NB * (DD / TD), 256, 0, stream>>>(x, w, b, rinv, out);
}

// Round 3
// 26.073 us; speedup vs baseline: 1.5902x; 1.5902x over previous
//
#include <hip/hip_runtime.h>
#include <math.h>

#define NB 4
#define CC 128
#define HW 784        // 28*28
#define KK 64
#define DD 512
#define TD 8          // d-rows per block

// Single fused kernel:
//   - streams x[n] once per block, accumulating BOTH the 1x1-conv dot products
//     (8 d-rows x 4 pixels per thread) AND the per-pixel sum-of-squares
//     (for the channel-wise L2 norm) in the same loop
//   - feat = rinv * dot + bias  -> staged in LDS
//   - per-(d) row softmax-weighted mean over P=784 via wave shuffle reduce
//   - vlad[n,k,d] is k-independent (softmax over spatial axis is invariant to
//     the per-(k,d) centroid shift), so lane k writes the broadcast value.
__global__ __launch_bounds__(256) void netvlad_fused_kernel(
    const float* __restrict__ x, const float* __restrict__ w,
    const float* __restrict__ b, float* __restrict__ out)
{
    __shared__ float w_s[TD][CC];        // 4 KB
    __shared__ float feat_s[TD][HW];     // 25 KB

    const int tid = threadIdx.x;
    const int n  = blockIdx.x >> 6;      // 64 d-groups per n
    const int d0 = (blockIdx.x & 63) * TD;

    // stage the 8x128 weight tile (contiguous 1024 floats)
    {
        const float* wsrc = w + (size_t)d0 * CC;
        for (int i = tid; i < TD * CC; i += 256) ((float*)w_s)[i] = wsrc[i];
    }
    __syncthreads();

    const float* xb = x + (size_t)n * CC * HW;
    float acc[TD][4];
    #pragma unroll
    for (int j = 0; j < TD; ++j)
        #pragma unroll
        for (int i = 0; i < 4; ++i) acc[j][i] = 0.f;
    float s0 = 0.f, s1 = 0.f, s2 = 0.f, s3 = 0.f;   // per-pixel sum of squares

    const bool tail = tid < (HW - 768);  // tid < 16 owns a 4th pixel

    // Main loop: thread owns pixels {tid, tid+256, tid+512, (tid+768)}
    #pragma unroll 4
    for (int c = 0; c < CC; ++c) {
        const float* xc = xb + (size_t)c * HW;
        float xv0 = xc[tid];
        float xv1 = xc[tid + 256];
        float xv2 = xc[tid + 512];
        float xv3 = tail ? xc[tid + 768] : 0.f;
        s0 = fmaf(xv0, xv0, s0);
        s1 = fmaf(xv1, xv1, s1);
        s2 = fmaf(xv2, xv2, s2);
        s3 = fmaf(xv3, xv3, s3);
        #pragma unroll
        for (int j = 0; j < TD; ++j) {
            float wv = w_s[j][c];        // same addr for all lanes -> LDS broadcast
            acc[j][0] = fmaf(wv, xv0, acc[j][0]);
            acc[j][1] = fmaf(wv, xv1, acc[j][1]);
            acc[j][2] = fmaf(wv, xv2, acc[j][2]);
            acc[j][3] = fmaf(wv, xv3, acc[j][3]);
        }
    }

    // rinv = 1 / max(sqrt(sumsq), eps), then feat = rinv*dot + bias -> LDS
    float r0 = 1.0f / fmaxf(sqrtf(s0), 1e-12f);
    float r1 = 1.0f / fmaxf(sqrtf(s1), 1e-12f);
    float r2 = 1.0f / fmaxf(sqrtf(s2), 1e-12f);
    float r3 = 1.0f / fmaxf(sqrtf(s3), 1e-12f);
    #pragma unroll
    for (int j = 0; j < TD; ++j) {
        float bj = b[d0 + j];
        feat_s[j][tid]       = fmaf(acc[j][0], r0, bj);
        feat_s[j][tid + 256] = fmaf(acc[j][1], r1, bj);
        feat_s[j][tid + 512] = fmaf(acc[j][2], r2, bj);
        if (tail) feat_s[j][tid + 768] = fmaf(acc[j][3], r3, bj);
    }
    __syncthreads();

    // Per-row softmax-weighted mean over P=784; each wave handles 2 rows.
    const int lane = tid & 63;
    const int wave = tid >> 6;
    #pragma unroll
    for (int jj = 0; jj < TD / 4; ++jj) {
        const int j = wave * (TD / 4) + jj;
        float m = -INFINITY;
        for (int p = lane; p < HW; p += 64) m = fmaxf(m, feat_s[j][p]);
        #pragma unroll
        for (int off = 32; off; off >>= 1) m = fmaxf(m, __shfl_xor(m, off, 64));
        float s = 0.f, ws = 0.f;
        for (int p = lane; p < HW; p += 64) {
            float f = feat_s[j][p];
            float e = __expf(f - m);
            s += e;
            ws = fmaf(e, f, ws);
        }
        #pragma unroll
        for (int off = 32; off; off >>= 1) {
            s  += __shfl_xor(s, off, 64);
            ws += __shfl_xor(ws, off, 64);
        }
        float g = ws / s;
        // vlad[n,k,d] = g for all k: lane writes k = lane
        out[(size_t)n * KK * DD + (size_t)lane * DD + (d0 + j)] = g;
    }
}

extern "C" void kernel_launch(void* const* d_in, const int* in_sizes, int n_in,
                              void* d_out, int out_size, void* d_ws, size_t ws_size,
                              hipStream_t stream) {
    const float* x = (const float*)d_in[0];   // (4,128,28,28)
    const float* w = (const float*)d_in[1];   // (512,128)
    const float* b = (const float*)d_in[2];   // (512,)
    // d_in[3] = centroids (64,512): provably unused — softmax over the spatial
    // axis is invariant to the per-(k,d) constant shift, so vlad[n,k,d] is
    // identical for all k.
    float* out = (float*)d_out;               // (4,64,512) fp32

    netvlad_fused_kernel<<<NB * (DD / TD), 256, 0, stream>>>(x, w, b, out);
}

// Round 4
// 17.521 us; speedup vs baseline: 2.3664x; 1.4881x over previous
//
#include <hip/hip_runtime.h>
#include <math.h>

#define NB 4
#define CC 128
#define HW 784        // 28*28
#define KK 64
#define DD 512
#define TD 8          // d-rows per block
#define BLK 832       // 13 waves; >= HW so each thread owns <=1 pixel

// Single fused kernel, one block per (n, 8-d-row group), 13 waves for TLP:
//   - thread t owns pixel p=t (t<784): streams x[n,:,p], accumulating the
//     8 conv dot-products AND the per-pixel sum-of-squares in one pass
//   - feat = rinv*dot + bias staged in LDS
//   - waves 0..7 each do one row's softmax-weighted mean over P=784
//   - vlad[n,k,d] is k-independent (softmax over the spatial axis is invariant
//     to the per-(k,d) centroid shift) -> broadcast write via LDS
__global__ __launch_bounds__(BLK) void netvlad_fused_kernel(
    const float* __restrict__ x, const float* __restrict__ w,
    const float* __restrict__ b, float* __restrict__ out)
{
    __shared__ float w_s[CC][TD];        // 4 KB, transposed: [c][j]
    __shared__ float feat_s[TD][HW];     // 25 KB
    __shared__ float g_s[TD];

    const int tid = threadIdx.x;
    const int n  = blockIdx.x >> 6;      // 64 d-groups per n
    const int d0 = (blockIdx.x & 63) * TD;
    const bool act = tid < HW;

    // stage the 8x128 weight tile transposed (one-time, 4 KB)
    for (int i = tid; i < CC * TD; i += BLK) {
        int c = i >> 3, j = i & 7;
        w_s[c][j] = w[(size_t)(d0 + j) * CC + c];
    }
    __syncthreads();

    // GEMM + sumsq main loop: 1 pixel/thread, 13 waves hide load latency
    const float* xp = x + (size_t)n * CC * HW + (act ? tid : 0);
    float acc[TD];
    #pragma unroll
    for (int j = 0; j < TD; ++j) acc[j] = 0.f;
    float sq = 0.f;

    #pragma unroll 4
    for (int c = 0; c < CC; ++c) {
        float xv = xp[(size_t)c * HW];                    // coalesced dword
        float4 wlo = *(const float4*)&w_s[c][0];          // broadcast b128
        float4 whi = *(const float4*)&w_s[c][4];          // broadcast b128
        sq = fmaf(xv, xv, sq);
        acc[0] = fmaf(wlo.x, xv, acc[0]);
        acc[1] = fmaf(wlo.y, xv, acc[1]);
        acc[2] = fmaf(wlo.z, xv, acc[2]);
        acc[3] = fmaf(wlo.w, xv, acc[3]);
        acc[4] = fmaf(whi.x, xv, acc[4]);
        acc[5] = fmaf(whi.y, xv, acc[5]);
        acc[6] = fmaf(whi.z, xv, acc[6]);
        acc[7] = fmaf(whi.w, xv, acc[7]);
    }

    if (act) {
        float r = 1.0f / fmaxf(sqrtf(sq), 1e-12f);
        #pragma unroll
        for (int j = 0; j < TD; ++j)
            feat_s[j][tid] = fmaf(acc[j], r, b[d0 + j]);
    }
    __syncthreads();

    // Per-row softmax-weighted mean over P=784; wave j (j<8) handles row j.
    const int lane = tid & 63;
    const int wave = tid >> 6;
    if (wave < TD) {
        const int j = wave;
        float m = -INFINITY;
        for (int p = lane; p < HW; p += 64) m = fmaxf(m, feat_s[j][p]);
        #pragma unroll
        for (int off = 32; off; off >>= 1) m = fmaxf(m, __shfl_xor(m, off, 64));
        float s = 0.f, ws = 0.f;
        for (int p = lane; p < HW; p += 64) {
            float f = feat_s[j][p];
            float e = __expf(f - m);
            s += e;
            ws = fmaf(e, f, ws);
        }
        #pragma unroll
        for (int off = 32; off; off >>= 1) {
            s  += __shfl_xor(s, off, 64);
            ws += __shfl_xor(ws, off, 64);
        }
        if (lane == 0) g_s[j] = ws / s;
    }
    __syncthreads();

    // Broadcast across k with a coalesced write: block owns out[n, :, d0:d0+8]
    if (tid < KK * TD) {
        int k = tid >> 3, j = tid & 7;
        out[(size_t)n * KK * DD + (size_t)k * DD + d0 + j] = g_s[j];
    }
}

extern "C" void kernel_launch(void* const* d_in, const int* in_sizes, int n_in,
                              void* d_out, int out_size, void* d_ws, size_t ws_size,
                              hipStream_t stream) {
    const float* x = (const float*)d_in[0];   // (4,128,28,28)
    const float* w = (const float*)d_in[1];   // (512,128)
    const float* b = (const float*)d_in[2];   // (512,)
    // d_in[3] = centroids (64,512): provably unused — softmax over the spatial
    // axis is invariant to the per-(k,d) constant shift, so vlad[n,k,d] is
    // identical for all k.
    float* out = (float*)d_out;               // (4,64,512) fp32

    netvlad_fused_kernel<<<NB * (DD / TD), BLK, 0, stream>>>(x, w, b, out);
}